// Round 5
// baseline (470.907 us; speedup 1.0000x reference)
//
#include <hip/hip_runtime.h>
#include <hip/hip_bf16.h>
#include <math.h>

// Problem constants
#define B_  4
#define S_  2048
#define D_  1024
#define H_  16
#define HD_ 64

typedef __bf16 bf16;
typedef __bf16 bf16x4 __attribute__((ext_vector_type(4)));
typedef __bf16 bf16x8 __attribute__((ext_vector_type(8)));
typedef float  floatx4 __attribute__((ext_vector_type(4)));

// log2(e)/8: folds the 1/sqrt(64) attention scale AND the exp->exp2 change
// of base into the Q projection epilogue.
#define QSCALE 0.18033688011112042f

// Async global->LDS DMA, 16B/lane. LDS dest = wave-uniform base + lane*16.
__device__ __forceinline__ void async_load16(const bf16* g, bf16* l) {
  __builtin_amdgcn_global_load_lds(
      (const __attribute__((address_space(1))) void*)g,
      (__attribute__((address_space(3))) void*)l, 16, 0, 0);
}

// ---------------------------------------------------------------------------
// fp32 -> bf16 cast for BOTH X inputs in one launch (8192 blocks each)
// ---------------------------------------------------------------------------
__global__ __launch_bounds__(256) void cast_both(
    const float* __restrict__ ina, bf16* __restrict__ outa,
    const float* __restrict__ inb, bf16* __restrict__ outb) {
  int bid = blockIdx.x;
  const float* in;
  bf16* out;
  int i;
  if (bid < 8192) { in = ina; out = outa; i = (bid * 256 + threadIdx.x) * 4; }
  else            { in = inb; out = outb; i = ((bid - 8192) * 256 + threadIdx.x) * 4; }
  float4 v = *reinterpret_cast<const float4*>(in + i);
  bf16x4 o;
  o[0] = (bf16)v.x; o[1] = (bf16)v.y; o[2] = (bf16)v.z; o[3] = (bf16)v.w;
  *reinterpret_cast<bf16x4*>(out + i) = o;
}

// ---------------------------------------------------------------------------
// fp32 [K][N] -> bf16 [N][K] transpose+cast for all 3 weights in one launch.
// K=1024 for all; N=1024 (q_w), 2048 (kv_w), 1024 (out_w).
// ---------------------------------------------------------------------------
__global__ __launch_bounds__(256) void transcast_all(
    const float* __restrict__ qw, bf16* __restrict__ qwT,
    const float* __restrict__ kvw, bf16* __restrict__ kvwT,
    const float* __restrict__ ow, bf16* __restrict__ owT) {
  __shared__ float tile[32][33];
  int bid = blockIdx.x;
  const float* in; bf16* out; int N, lb;
  if (bid < 1024)      { in = qw;  out = qwT;  N = 1024; lb = bid; }
  else if (bid < 3072) { in = kvw; out = kvwT; N = 2048; lb = bid - 1024; }
  else                 { in = ow;  out = owT;  N = 1024; lb = bid - 3072; }
  int nx = N >> 5;
  int n0 = (lb % nx) * 32, k0 = (lb / nx) * 32;
  int tx = threadIdx.x & 31, ty = threadIdx.x >> 5;  // 32 x 8
  #pragma unroll
  for (int i = ty; i < 32; i += 8)
    tile[i][tx] = in[(size_t)(k0 + i) * N + n0 + tx];
  __syncthreads();
  #pragma unroll
  for (int i = ty; i < 32; i += 8)
    out[(size_t)(n0 + i) * 1024 + k0 + tx] = (bf16)tile[tx][i];
}

// ---------------------------------------------------------------------------
// bf16 GEMM body, m97 structure: C[M,N] = A[M,K] @ Bt[N,K]^T + bias[N]
// 128x128 tile, BK=64, global_load_lds(16B) staging, XOR-swizzled LDS.
// MODE 0: fp32 out row-major [M,N]
// MODE 1: bf16 out in Q layout [B,H,S,HD], scaled by QSCALE (N==1024)
// MODE 2: bf16 out; K half -> [B,H,S,HD]; V half -> TRANSPOSED [B,H,HD,S]
// ---------------------------------------------------------------------------
template <int MODE>
__device__ __forceinline__ void gemm_body(
    const bf16* __restrict__ A, const bf16* __restrict__ Bt,
    const float* __restrict__ bias, void* __restrict__ out,
    int M, int N, int K, int bx, int by,
    bf16 (*As)[64], bf16 (*Bs)[64]) {
  const int tid  = threadIdx.x;
  const int m0   = by * 128;
  const int n0   = bx * 128;
  const int w    = tid >> 6;
  const int lane = tid & 63;
  const int lr   = lane & 15;
  const int lq   = lane >> 4;
  const int wm   = (w >> 1) * 64;
  const int wn   = (w & 1) * 64;

  const int srow = lane >> 3;
  const int sg   = (lane & 7) ^ srow;
  const bf16* aptr = A  + (size_t)(m0 + 32 * w + srow) * K + 8 * sg;
  const bf16* bptr = Bt + (size_t)(n0 + 32 * w + srow) * K + 8 * sg;

  floatx4 acc[4][4];
  #pragma unroll
  for (int i = 0; i < 4; i++)
    #pragma unroll
    for (int j = 0; j < 4; j++)
      acc[i][j] = floatx4{0.f, 0.f, 0.f, 0.f};

  for (int k0 = 0; k0 < K; k0 += 64) {
    __syncthreads();
    #pragma unroll
    for (int p = 0; p < 4; p++) {
      async_load16(aptr + (size_t)8 * p * K + k0, &As[32 * w + 8 * p][0]);
      async_load16(bptr + (size_t)8 * p * K + k0, &Bs[32 * w + 8 * p][0]);
    }
    __syncthreads();  // drains vmcnt(0): staged data visible
    #pragma unroll
    for (int kc = 0; kc < 2; kc++) {
      const int sw = 8 * ((kc * 4 + lq) ^ (lr & 7));
      bf16x8 af[4], bfv[4];
      #pragma unroll
      for (int t = 0; t < 4; t++)
        af[t] = *reinterpret_cast<const bf16x8*>(&As[wm + 16 * t + lr][sw]);
      #pragma unroll
      for (int t = 0; t < 4; t++)
        bfv[t] = *reinterpret_cast<const bf16x8*>(&Bs[wn + 16 * t + lr][sw]);
      #pragma unroll
      for (int i = 0; i < 4; i++)
        #pragma unroll
        for (int j = 0; j < 4; j++)
          acc[i][j] = __builtin_amdgcn_mfma_f32_16x16x32_bf16(af[i], bfv[j], acc[i][j], 0, 0, 0);
    }
  }

  // epilogue (C/D: col=lane&15, row=(lane>>4)*4+reg)
  #pragma unroll
  for (int i = 0; i < 4; i++) {
    int row_base = m0 + wm + 16 * i + lq * 4;
    #pragma unroll
    for (int j = 0; j < 4; j++) {
      int col = n0 + wn + 16 * j + lr;
      float bv = bias[col];
      if (MODE == 2 && col >= 1024) {
        int b = row_base >> 11, s0 = row_base & 2047;
        int c = col - 1024, h = c >> 6, d = c & 63;
        bf16* Vt = (bf16*)out + (size_t)B_ * H_ * S_ * HD_;
        bf16x4 pk;
        #pragma unroll
        for (int r = 0; r < 4; r++) pk[r] = (bf16)(acc[i][j][r] + bv);
        *reinterpret_cast<bf16x4*>(
            &Vt[(((size_t)b * H_ + h) * HD_ + d) * S_ + s0]) = pk;
        continue;
      }
      #pragma unroll
      for (int r = 0; r < 4; r++) {
        int row = row_base + r;
        float v = acc[i][j][r] + bv;
        if (MODE == 0) {
          ((float*)out)[(size_t)row * N + col] = v;
        } else if (MODE == 1) {
          int b = row >> 11, s = row & 2047;
          int h = col >> 6, d = col & 63;
          ((bf16*)out)[(((size_t)b * H_ + h) * S_ + s) * HD_ + d] =
              (bf16)(v * QSCALE);
        } else {
          int b = row >> 11, s = row & 2047;
          int h = col >> 6, d = col & 63;
          ((bf16*)out)[(((size_t)b * H_ + h) * S_ + s) * HD_ + d] = (bf16)v;
        }
      }
    }
  }
}

// out-projection GEMM (fp32 out), plain grid
__global__ __launch_bounds__(256) void gemm_out(
    const bf16* __restrict__ A, const bf16* __restrict__ Bt,
    const float* __restrict__ bias, void* __restrict__ out,
    int M, int N, int K) {
  __shared__ bf16 As[128][64];
  __shared__ bf16 Bs[128][64];
  gemm_body<0>(A, Bt, bias, out, M, N, K, blockIdx.x, blockIdx.y, As, Bs);
}

// Merged Q-projection + KV-projection in ONE launch (block-range dispatch).
__global__ __launch_bounds__(256) void gemm_qkv(
    const bf16* __restrict__ Xq, const bf16* __restrict__ qwT,
    const float* __restrict__ q_b, bf16* __restrict__ Qb,
    const bf16* __restrict__ Xkv, const bf16* __restrict__ kvwT,
    const float* __restrict__ kv_b, bf16* __restrict__ KVb) {
  __shared__ bf16 As[128][64];
  __shared__ bf16 Bs[128][64];
  int bid = blockIdx.x;
  if (bid < 512) {
    gemm_body<1>(Xq, qwT, q_b, Qb, 8192, 1024, 1024, bid & 7, bid >> 3, As, Bs);
  } else {
    int b2 = bid - 512;
    gemm_body<2>(Xkv, kvwT, kv_b, KVb, 8192, 2048, 1024, b2 & 15, b2 >> 4, As, Bs);
  }
}

// ---------------------------------------------------------------------------
// Attention v5: 512 q-rows/block, 8 waves (wave w owns 64 q as 4 groups of
// 16), ONE shared K/V double-buffer per block. Two old 256-row blocks of the
// same head are fused so K/V staging per wave HALVES and occupancy doubles:
// 256 blocks x 8 waves = 2048 waves at 2 blocks/CU (64KB LDS) = 4 waves/SIMD
// (was 2 — the structural cap at 64 q/wave with 256-row blocks).
// P is [64q][32keys] = 4KB/wave: the kc=0 PV B-fragments (bp0) are loaded to
// registers BEFORE QK^T t=2,3 overwrites the buffer with keys 32-63
// (read-before-write is compiler-ordered via alias + in-order per-wave LDS,
// fenced with lgkmcnt(0) + wave_barrier). V kc=0 fragments are re-read
// inline (vts not overwritten until syncthreads) to keep VGPR < 128.
// bh-major grid: the 4 q-tiles of a head share an XCD -> K/V L2-resident.
// S^T = K@Q^T; p = exp2(s) (scale folded into Q; no running max needed).
// O^T = V^T@P^T with V^T precomputed by the KV GEMM.
// LDS: kv dbuf 32 KB + P 8x4KB = 64 KB -> 2 blocks/CU.
// ---------------------------------------------------------------------------
__global__ __launch_bounds__(512, 4) void attn_kernel(
    const bf16* __restrict__ Q, const bf16* __restrict__ Kb,
    const bf16* __restrict__ Vt, bf16* __restrict__ out) {
  __shared__ bf16 smem[32768];  // [2][ks 4096 | vts 4096] | P 8 x 2048

  const int tid  = threadIdx.x;
  const int w    = tid >> 6;            // 0..7
  const int lane = tid & 63;
  const int lr   = lane & 15;
  const int lq   = lane >> 4;
  const int bh   = blockIdx.x;          // x-major -> head's q-tiles same XCD
  const int q0   = blockIdx.y * 512;
  const size_t base = (size_t)bh * S_ * HD_;

  bf16* pw = smem + 16384 + w * 2048;   // wave's P: [64 q][32 keys], swizzled

  const int srow = lane >> 3;           // 0..7
  const int sg   = (lane & 7) ^ srow;

  // K/V staging: wave w covers tile rows [8w, 8w+8), ONE DMA instr each
  const bf16* kptr = Kb + base + (size_t)(8 * w + srow) * HD_ + 8 * sg;
  const bf16* vptr = Vt + base + (size_t)(8 * w + srow) * S_  + 8 * sg;

  // stage tile 0 into buf 0
  async_load16(kptr, smem + 8 * w * 64);
  async_load16(vptr, smem + 4096 + 8 * w * 64);

  // Q fragments from global (B-layout: n=lr -> q row, k=32kc+8lq+j)
  bf16x8 bq[4][2];
  #pragma unroll
  for (int g = 0; g < 4; g++) {
    const bf16* qrow = Q + base + (size_t)(q0 + 64 * w + 16 * g + lr) * HD_;
    bq[g][0] = *reinterpret_cast<const bf16x8*>(qrow + lq * 8);
    bq[g][1] = *reinterpret_cast<const bf16x8*>(qrow + 32 + lq * 8);
  }

  const int sw0 = 8 * ((0 + lq) ^ (lr & 7));
  const int sw1 = 8 * ((4 + lq) ^ (lr & 7));
  const int pxr = lr & 3;
  const int pcolbase = 4 * (lq & 1);
  const int prd = 8 * (lq ^ pxr);       // P read col (keys 8lq..8lq+7)

  float l_i[4] = {0.f, 0.f, 0.f, 0.f};
  floatx4 o_acc[4][4];
  #pragma unroll
  for (int g = 0; g < 4; g++)
    #pragma unroll
    for (int t = 0; t < 4; t++) o_acc[g][t] = floatx4{0.f, 0.f, 0.f, 0.f};

  __syncthreads();  // drain: tile 0 staged (bq loads waited via vmcnt too)

  // pointer-stepped prefetch bases (tile 1)
  const bf16* kpf = kptr + (size_t)64 * HD_;
  const bf16* vpf = vptr + 64;

  const int NIT = S_ / 64;
  for (int it = 0; it < NIT; it++) {
    bf16* ks  = smem + (it & 1) * 8192;
    bf16* vts = ks + 4096;

    // prefetch tile it+1 into the other buffer (drained at loop-end barrier)
    if (it + 1 < NIT) {
      bf16* ksn = smem + ((it + 1) & 1) * 8192;
      async_load16(kpf, ksn + 8 * w * 64);
      async_load16(vpf, ksn + 4096 + 8 * w * 64);
    }

    // QK^T + exp + P-write for 16-key block t; buffer slot = t&1
    auto qkt = [&](int t) {
      bf16x8 ak0 = *reinterpret_cast<const bf16x8*>(ks + (16 * t + lr) * 64 + sw0);
      bf16x8 ak1 = *reinterpret_cast<const bf16x8*>(ks + (16 * t + lr) * 64 + sw1);
      floatx4 sc[4];
      #pragma unroll
      for (int g = 0; g < 4; g++) {
        sc[g] = __builtin_amdgcn_mfma_f32_16x16x32_bf16(ak0, bq[g][0],
                    floatx4{0.f, 0.f, 0.f, 0.f}, 0, 0, 0);
        sc[g] = __builtin_amdgcn_mfma_f32_16x16x32_bf16(ak1, bq[g][1], sc[g], 0, 0, 0);
      }
      const int pcol = 8 * ((2 * (t & 1) + (lq >> 1)) ^ pxr) + pcolbase;
      #pragma unroll
      for (int g = 0; g < 4; g++) {
        bf16x4 pk;
        float lsum = 0.f;
        #pragma unroll
        for (int r = 0; r < 4; r++) {
          float p = __builtin_amdgcn_exp2f(sc[g][r]);
          lsum += p;
          pk[r] = (bf16)p;
        }
        l_i[g] += lsum;
        *reinterpret_cast<bf16x4*>(&pw[(16 * g + lr) * 32 + pcol]) = pk;
      }
    };

    // ---- phase A: QK^T keys 0-31 -> P buffer ----
    qkt(0);
    qkt(1);
    __builtin_amdgcn_wave_barrier();  // pin same-wave ds_write -> ds_read

    // snapshot kc=0 P-fragments to regs before keys 32-63 overwrite buffer
    bf16x8 bp0[4];
    #pragma unroll
    for (int g = 0; g < 4; g++)
      bp0[g] = *reinterpret_cast<const bf16x8*>(&pw[(16 * g + lr) * 32 + prd]);
    asm volatile("s_waitcnt lgkmcnt(0)" ::: "memory");  // reads returned
    __builtin_amdgcn_wave_barrier();

    // ---- phase B: QK^T keys 32-63 (overwrite P) overlapped with PV kc=0 ----
    qkt(2);
    __builtin_amdgcn_s_setprio(1);
    #pragma unroll
    for (int t2 = 0; t2 < 2; t2++) {
      bf16x8 av = *reinterpret_cast<const bf16x8*>(vts + (16 * t2 + lr) * 64 + sw0);
      #pragma unroll
      for (int g = 0; g < 4; g++)
        o_acc[g][t2] = __builtin_amdgcn_mfma_f32_16x16x32_bf16(av, bp0[g], o_acc[g][t2], 0, 0, 0);
    }
    __builtin_amdgcn_s_setprio(0);
    qkt(3);
    __builtin_amdgcn_s_setprio(1);
    #pragma unroll
    for (int t2 = 2; t2 < 4; t2++) {
      bf16x8 av = *reinterpret_cast<const bf16x8*>(vts + (16 * t2 + lr) * 64 + sw0);
      #pragma unroll
      for (int g = 0; g < 4; g++)
        o_acc[g][t2] = __builtin_amdgcn_mfma_f32_16x16x32_bf16(av, bp0[g], o_acc[g][t2], 0, 0, 0);
    }
    __builtin_amdgcn_s_setprio(0);
    __builtin_amdgcn_wave_barrier();  // pin t=2,3 P-writes -> kc=1 reads

    // ---- phase C: PV kc=1 (keys 32-63) ----
    {
      bf16x8 bp1[4];
      #pragma unroll
      for (int g = 0; g < 4; g++)
        bp1[g] = *reinterpret_cast<const bf16x8*>(&pw[(16 * g + lr) * 32 + prd]);
      __builtin_amdgcn_s_setprio(1);
      #pragma unroll
      for (int t2 = 0; t2 < 4; t2++) {
        bf16x8 av = *reinterpret_cast<const bf16x8*>(vts + (16 * t2 + lr) * 64 + sw1);
        #pragma unroll
        for (int g = 0; g < 4; g++)
          o_acc[g][t2] = __builtin_amdgcn_mfma_f32_16x16x32_bf16(av, bp1[g], o_acc[g][t2], 0, 0, 0);
      }
      __builtin_amdgcn_s_setprio(0);
    }

    kpf += (size_t)64 * HD_;
    vpf += 64;
    __syncthreads();  // frees cur buf; drains prefetch -> tile it+1 ready
  }

  // finish denom: sum across the 4 lq groups sharing q=lr
  #pragma unroll
  for (int g = 0; g < 4; g++) {
    l_i[g] += __shfl_xor(l_i[g], 16, 64);
    l_i[g] += __shfl_xor(l_i[g], 32, 64);
  }

  // epilogue: out[b, s=q0+64w+16g+lr, h*64 + 16t + 4lq + r]
  const int b = bh >> 4, h = bh & 15;
  #pragma unroll
  for (int g = 0; g < 4; g++) {
    const float inv = 1.0f / l_i[g];
    const int qrow = q0 + 64 * w + 16 * g + lr;
    bf16* orow = out + ((size_t)b * S_ + qrow) * D_ + h * HD_;
    #pragma unroll
    for (int t = 0; t < 4; t++) {
      bf16x4 pk;
      #pragma unroll
      for (int r = 0; r < 4; r++) pk[r] = (bf16)(o_acc[g][t][r] * inv);
      *reinterpret_cast<bf16x4*>(&orow[16 * t + lq * 4]) = pk;
    }
  }
}

// ---------------------------------------------------------------------------
extern "C" void kernel_launch(void* const* d_in, const int* in_sizes, int n_in,
                              void* d_out, int out_size, void* d_ws, size_t ws_size,
                              hipStream_t stream) {
  const float* X_Q   = (const float*)d_in[0];
  const float* X_KV  = (const float*)d_in[1];
  const float* q_w   = (const float*)d_in[2];
  const float* q_b   = (const float*)d_in[3];
  const float* kv_w  = (const float*)d_in[4];
  const float* kv_b  = (const float*)d_in[5];
  const float* out_w = (const float*)d_in[6];
  const float* out_b = (const float*)d_in[7];
  float* out = (float*)d_out;

  char* ws = (char*)d_ws;
  const size_t MB = 1024 * 1024;
  bf16* Xq   = (bf16*)(ws + 0);         // 16MB (reused as attn output later)
  bf16* Xkv  = (bf16*)(ws + 16 * MB);   // 16MB
  bf16* Qb   = (bf16*)(ws + 32 * MB);   // 16MB  [B,H,S,HD] (pre-scaled)
  bf16* Kb   = (bf16*)(ws + 48 * MB);   // 16MB  [B,H,S,HD]; Vt follows at +16MB
  bf16* qwT  = (bf16*)(ws + 80 * MB);   // 2MB   [N=1024][K=1024]
  bf16* kvwT = (bf16*)(ws + 82 * MB);   // 4MB   [N=2048][K=1024]
  bf16* owT  = (bf16*)(ws + 86 * MB);   // 2MB
  bf16* Vt   = Kb + (size_t)B_ * H_ * S_ * HD_;  // [B,H,HD,S]
  bf16* attn = Xq;                       // alias: X_Q bf16 dead after GEMM1

  cast_both<<<16384, 256, 0, stream>>>(X_Q, Xq, X_KV, Xkv);
  transcast_all<<<4096, 256, 0, stream>>>(q_w, qwT, kv_w, kvwT, out_w, owT);

  // merged: Q = (Xq @ q_w + q_b)*QSCALE  and  KV = Xkv @ kv_w + kv_b
  gemm_qkv<<<1536, 256, 0, stream>>>(Xq, qwT, q_b, Qb, Xkv, kvwT, kv_b, Kb);
  // attention (512 q-rows per block, 8 waves; bh-major grid for XCD/L2)
  attn_kernel<<<dim3(64, 4), 512, 0, stream>>>(Qb, Kb, Vt, attn);
  // out = attn @ out_w + out_b  (fp32)
  gemm_out<<<dim3(8, 64), 256, 0, stream>>>(attn, owT, out_b, out, 8192, 1024, 1024);
}

// Round 6
// 305.673 us; speedup vs baseline: 1.5406x; 1.5406x over previous
//
#include <hip/hip_runtime.h>
#include <hip/hip_bf16.h>
#include <math.h>

// Problem constants
#define B_  4
#define S_  2048
#define D_  1024
#define H_  16
#define HD_ 64

typedef __bf16 bf16;
typedef __bf16 bf16x4 __attribute__((ext_vector_type(4)));
typedef __bf16 bf16x8 __attribute__((ext_vector_type(8)));
typedef float  floatx4 __attribute__((ext_vector_type(4)));

// log2(e)/8: folds the 1/sqrt(64) attention scale AND the exp->exp2 change
// of base into the Q projection epilogue.
#define QSCALE 0.18033688011112042f

// Async global->LDS DMA, 16B/lane. LDS dest = wave-uniform base + lane*16.
__device__ __forceinline__ void async_load16(const bf16* g, bf16* l) {
  __builtin_amdgcn_global_load_lds(
      (const __attribute__((address_space(1))) void*)g,
      (__attribute__((address_space(3))) void*)l, 16, 0, 0);
}

// ---------------------------------------------------------------------------
// fp32 -> bf16 cast for BOTH X inputs in one launch (8192 blocks each)
// ---------------------------------------------------------------------------
__global__ __launch_bounds__(256) void cast_both(
    const float* __restrict__ ina, bf16* __restrict__ outa,
    const float* __restrict__ inb, bf16* __restrict__ outb) {
  int bid = blockIdx.x;
  const float* in;
  bf16* out;
  int i;
  if (bid < 8192) { in = ina; out = outa; i = (bid * 256 + threadIdx.x) * 4; }
  else            { in = inb; out = outb; i = ((bid - 8192) * 256 + threadIdx.x) * 4; }
  float4 v = *reinterpret_cast<const float4*>(in + i);
  bf16x4 o;
  o[0] = (bf16)v.x; o[1] = (bf16)v.y; o[2] = (bf16)v.z; o[3] = (bf16)v.w;
  *reinterpret_cast<bf16x4*>(out + i) = o;
}

// ---------------------------------------------------------------------------
// fp32 [K][N] -> bf16 [N][K] transpose+cast for all 3 weights in one launch.
// K=1024 for all; N=1024 (q_w), 2048 (kv_w), 1024 (out_w).
// ---------------------------------------------------------------------------
__global__ __launch_bounds__(256) void transcast_all(
    const float* __restrict__ qw, bf16* __restrict__ qwT,
    const float* __restrict__ kvw, bf16* __restrict__ kvwT,
    const float* __restrict__ ow, bf16* __restrict__ owT) {
  __shared__ float tile[32][33];
  int bid = blockIdx.x;
  const float* in; bf16* out; int N, lb;
  if (bid < 1024)      { in = qw;  out = qwT;  N = 1024; lb = bid; }
  else if (bid < 3072) { in = kvw; out = kvwT; N = 2048; lb = bid - 1024; }
  else                 { in = ow;  out = owT;  N = 1024; lb = bid - 3072; }
  int nx = N >> 5;
  int n0 = (lb % nx) * 32, k0 = (lb / nx) * 32;
  int tx = threadIdx.x & 31, ty = threadIdx.x >> 5;  // 32 x 8
  #pragma unroll
  for (int i = ty; i < 32; i += 8)
    tile[i][tx] = in[(size_t)(k0 + i) * N + n0 + tx];
  __syncthreads();
  #pragma unroll
  for (int i = ty; i < 32; i += 8)
    out[(size_t)(n0 + i) * 1024 + k0 + tx] = (bf16)tile[tx][i];
}

// ---------------------------------------------------------------------------
// bf16 GEMM body, m97 structure: C[M,N] = A[M,K] @ Bt[N,K]^T + bias[N]
// 128x128 tile, BK=64, global_load_lds(16B) staging, XOR-swizzled LDS.
// MODE 0: fp32 out row-major [M,N]
// MODE 1: bf16 out in Q layout [B,H,S,HD], scaled by QSCALE (N==1024)
// MODE 2: bf16 out; K half -> [B,H,S,HD]; V half -> TRANSPOSED [B,H,HD,S]
// ---------------------------------------------------------------------------
template <int MODE>
__device__ __forceinline__ void gemm_body(
    const bf16* __restrict__ A, const bf16* __restrict__ Bt,
    const float* __restrict__ bias, void* __restrict__ out,
    int M, int N, int K, int bx, int by,
    bf16 (*As)[64], bf16 (*Bs)[64]) {
  const int tid  = threadIdx.x;
  const int m0   = by * 128;
  const int n0   = bx * 128;
  const int w    = tid >> 6;
  const int lane = tid & 63;
  const int lr   = lane & 15;
  const int lq   = lane >> 4;
  const int wm   = (w >> 1) * 64;
  const int wn   = (w & 1) * 64;

  const int srow = lane >> 3;
  const int sg   = (lane & 7) ^ srow;
  const bf16* aptr = A  + (size_t)(m0 + 32 * w + srow) * K + 8 * sg;
  const bf16* bptr = Bt + (size_t)(n0 + 32 * w + srow) * K + 8 * sg;

  floatx4 acc[4][4];
  #pragma unroll
  for (int i = 0; i < 4; i++)
    #pragma unroll
    for (int j = 0; j < 4; j++)
      acc[i][j] = floatx4{0.f, 0.f, 0.f, 0.f};

  for (int k0 = 0; k0 < K; k0 += 64) {
    __syncthreads();
    #pragma unroll
    for (int p = 0; p < 4; p++) {
      async_load16(aptr + (size_t)8 * p * K + k0, &As[32 * w + 8 * p][0]);
      async_load16(bptr + (size_t)8 * p * K + k0, &Bs[32 * w + 8 * p][0]);
    }
    __syncthreads();  // drains vmcnt(0): staged data visible
    #pragma unroll
    for (int kc = 0; kc < 2; kc++) {
      const int sw = 8 * ((kc * 4 + lq) ^ (lr & 7));
      bf16x8 af[4], bfv[4];
      #pragma unroll
      for (int t = 0; t < 4; t++)
        af[t] = *reinterpret_cast<const bf16x8*>(&As[wm + 16 * t + lr][sw]);
      #pragma unroll
      for (int t = 0; t < 4; t++)
        bfv[t] = *reinterpret_cast<const bf16x8*>(&Bs[wn + 16 * t + lr][sw]);
      #pragma unroll
      for (int i = 0; i < 4; i++)
        #pragma unroll
        for (int j = 0; j < 4; j++)
          acc[i][j] = __builtin_amdgcn_mfma_f32_16x16x32_bf16(af[i], bfv[j], acc[i][j], 0, 0, 0);
    }
  }

  // epilogue (C/D: col=lane&15, row=(lane>>4)*4+reg)
  #pragma unroll
  for (int i = 0; i < 4; i++) {
    int row_base = m0 + wm + 16 * i + lq * 4;
    #pragma unroll
    for (int j = 0; j < 4; j++) {
      int col = n0 + wn + 16 * j + lr;
      float bv = bias[col];
      if (MODE == 2 && col >= 1024) {
        int b = row_base >> 11, s0 = row_base & 2047;
        int c = col - 1024, h = c >> 6, d = c & 63;
        bf16* Vt = (bf16*)out + (size_t)B_ * H_ * S_ * HD_;
        bf16x4 pk;
        #pragma unroll
        for (int r = 0; r < 4; r++) pk[r] = (bf16)(acc[i][j][r] + bv);
        *reinterpret_cast<bf16x4*>(
            &Vt[(((size_t)b * H_ + h) * HD_ + d) * S_ + s0]) = pk;
        continue;
      }
      #pragma unroll
      for (int r = 0; r < 4; r++) {
        int row = row_base + r;
        float v = acc[i][j][r] + bv;
        if (MODE == 0) {
          ((float*)out)[(size_t)row * N + col] = v;
        } else if (MODE == 1) {
          int b = row >> 11, s = row & 2047;
          int h = col >> 6, d = col & 63;
          ((bf16*)out)[(((size_t)b * H_ + h) * S_ + s) * HD_ + d] =
              (bf16)(v * QSCALE);
        } else {
          int b = row >> 11, s = row & 2047;
          int h = col >> 6, d = col & 63;
          ((bf16*)out)[(((size_t)b * H_ + h) * S_ + s) * HD_ + d] = (bf16)v;
        }
      }
    }
  }
}

// out-projection GEMM (fp32 out), plain grid
__global__ __launch_bounds__(256) void gemm_out(
    const bf16* __restrict__ A, const bf16* __restrict__ Bt,
    const float* __restrict__ bias, void* __restrict__ out,
    int M, int N, int K) {
  __shared__ bf16 As[128][64];
  __shared__ bf16 Bs[128][64];
  gemm_body<0>(A, Bt, bias, out, M, N, K, blockIdx.x, blockIdx.y, As, Bs);
}

// Merged Q-projection + KV-projection in ONE launch (block-range dispatch).
__global__ __launch_bounds__(256) void gemm_qkv(
    const bf16* __restrict__ Xq, const bf16* __restrict__ qwT,
    const float* __restrict__ q_b, bf16* __restrict__ Qb,
    const bf16* __restrict__ Xkv, const bf16* __restrict__ kvwT,
    const float* __restrict__ kv_b, bf16* __restrict__ KVb) {
  __shared__ bf16 As[128][64];
  __shared__ bf16 Bs[128][64];
  int bid = blockIdx.x;
  if (bid < 512) {
    gemm_body<1>(Xq, qwT, q_b, Qb, 8192, 1024, 1024, bid & 7, bid >> 3, As, Bs);
  } else {
    int b2 = bid - 512;
    gemm_body<2>(Xkv, kvwT, kv_b, KVb, 8192, 2048, 1024, b2 & 15, b2 >> 4, As, Bs);
  }
}

// ---------------------------------------------------------------------------
// Attention v6: 512 q-rows/block, 8 waves (wave w owns 64 q as 4 groups of
// 16), ONE shared K/V double-buffer per block.
// Fixes v5's two faults:
//  (1) __launch_bounds__(512, 2): v5's (512,4) was interpreted as CUDA-style
//      min-BLOCKS/CU -> 8 waves/SIMD -> VGPR cap 64 -> massive scratch spills
//      (WRITE_SIZE 498MB, MfmaUtil 10%). (512,2) caps at 128 under CUDA
//      semantics (the 4-waves/SIMD budget) and 256 under waves/EU semantics.
//  (2) P swizzle: [64q][32keys]=4KB/wave with 8B-granule position XORed by
//      lr>>1 (3 bits, orthogonal to the lr&1 bank-window bit). Banking is
//      the data-width structural minimum (4 lanes per 2-bank pair), same as
//      the proven round-4 layout; v5's lr&3 swizzle was 4-way conflicted.
// Schedule per 64-key tile: A:QK^T(keys 0-31) | B:PV kc0 | C:QK^T(32-63,
// overwrite P) | D:PV kc1. No intra-wave overlap (measured null in r3);
// 4 waves/SIMD do the latency hiding. No cross-phase register snapshot.
// Occupancy: 256 blocks x 8 waves, 64KB LDS -> 2 blocks/CU = 4 waves/SIMD
// (round-4 was capped at 2 by grid AND LDS).
// bh-major grid: a head's q-tiles share an XCD -> K/V L2-resident
// (measured r3: FETCH 139MB -> 27.7MB).
// S^T = K@Q^T; p = exp2(s) (scale folded into Q; no running max needed).
// O^T = V^T@P^T with V^T precomputed by the KV GEMM.
// ---------------------------------------------------------------------------
__global__ __launch_bounds__(512, 2) void attn_kernel(
    const bf16* __restrict__ Q, const bf16* __restrict__ Kb,
    const bf16* __restrict__ Vt, bf16* __restrict__ out) {
  __shared__ bf16 smem[32768];  // [2][ks 4096 | vts 4096] | P 8 x 2048

  const int tid  = threadIdx.x;
  const int w    = tid >> 6;            // 0..7
  const int lane = tid & 63;
  const int lr   = lane & 15;
  const int lq   = lane >> 4;
  const int bh   = blockIdx.x;          // x-major -> head's q-tiles same XCD
  const int q0   = blockIdx.y * 512;
  const size_t base = (size_t)bh * S_ * HD_;

  bf16* pw = smem + 16384 + w * 2048;   // wave's P: [64 q][32 keys], swizzled

  const int srow = lane >> 3;           // 0..7
  const int sg   = (lane & 7) ^ srow;

  // K/V staging: wave w covers tile rows [8w, 8w+8), ONE DMA instr each
  const bf16* kptr = Kb + base + (size_t)(8 * w + srow) * HD_ + 8 * sg;
  const bf16* vptr = Vt + base + (size_t)(8 * w + srow) * S_  + 8 * sg;

  // stage tile 0 into buf 0
  async_load16(kptr, smem + 8 * w * 64);
  async_load16(vptr, smem + 4096 + 8 * w * 64);

  // Q fragments from global (B-layout: n=lr -> q row, k=32kc+8lq+j)
  bf16x8 bq[4][2];
  #pragma unroll
  for (int g = 0; g < 4; g++) {
    const bf16* qrow = Q + base + (size_t)(q0 + 64 * w + 16 * g + lr) * HD_;
    bq[g][0] = *reinterpret_cast<const bf16x8*>(qrow + lq * 8);
    bq[g][1] = *reinterpret_cast<const bf16x8*>(qrow + 32 + lq * 8);
  }

  const int sw0 = 8 * ((0 + lq) ^ (lr & 7));
  const int sw1 = 8 * ((4 + lq) ^ (lr & 7));
  const int plx = lr >> 1;              // 3-bit P-swizzle, orthogonal to lr&1

  float l_i[4] = {0.f, 0.f, 0.f, 0.f};
  floatx4 o_acc[4][4];
  #pragma unroll
  for (int g = 0; g < 4; g++)
    #pragma unroll
    for (int t = 0; t < 4; t++) o_acc[g][t] = floatx4{0.f, 0.f, 0.f, 0.f};

  __syncthreads();  // drain: tile 0 staged (bq loads waited via vmcnt too)

  // pointer-stepped prefetch bases (tile 1)
  const bf16* kpf = kptr + (size_t)64 * HD_;
  const bf16* vpf = vptr + 64;

  const int NIT = S_ / 64;
  for (int it = 0; it < NIT; it++) {
    bf16* ks  = smem + (it & 1) * 8192;
    bf16* vts = ks + 4096;

    // prefetch tile it+1 into the other buffer (drained at loop-end barrier)
    if (it + 1 < NIT) {
      bf16* ksn = smem + ((it + 1) & 1) * 8192;
      async_load16(kpf, ksn + 8 * w * 64);
      async_load16(vpf, ksn + 4096 + 8 * w * 64);
    }

    // QK^T + exp + P-write for 16-key block t; P slot group = 4*(t&1)+lq
    auto qkt = [&](int t) {
      bf16x8 ak0 = *reinterpret_cast<const bf16x8*>(ks + (16 * t + lr) * 64 + sw0);
      bf16x8 ak1 = *reinterpret_cast<const bf16x8*>(ks + (16 * t + lr) * 64 + sw1);
      floatx4 sc[4];
      #pragma unroll
      for (int g = 0; g < 4; g++) {
        sc[g] = __builtin_amdgcn_mfma_f32_16x16x32_bf16(ak0, bq[g][0],
                    floatx4{0.f, 0.f, 0.f, 0.f}, 0, 0, 0);
        sc[g] = __builtin_amdgcn_mfma_f32_16x16x32_bf16(ak1, bq[g][1], sc[g], 0, 0, 0);
      }
      const int pcol = 4 * ((4 * (t & 1) + lq) ^ plx);
      #pragma unroll
      for (int g = 0; g < 4; g++) {
        bf16x4 pk;
        float lsum = 0.f;
        #pragma unroll
        for (int r = 0; r < 4; r++) {
          float p = __builtin_amdgcn_exp2f(sc[g][r]);
          lsum += p;
          pk[r] = (bf16)p;
        }
        l_i[g] += lsum;
        *reinterpret_cast<bf16x4*>(&pw[(16 * g + lr) * 32 + pcol]) = pk;
      }
    };

    // PV for one 32-key half; P fragment assembled from two swizzled b64s
    auto pv = [&](int sw) {
      bf16x8 bp[4];
      #pragma unroll
      for (int g = 0; g < 4; g++) {
        union { bf16x4 h[2]; bf16x8 v; } f;
        f.h[0] = *reinterpret_cast<const bf16x4*>(
            &pw[(16 * g + lr) * 32 + 4 * ((2 * lq + 0) ^ plx)]);
        f.h[1] = *reinterpret_cast<const bf16x4*>(
            &pw[(16 * g + lr) * 32 + 4 * ((2 * lq + 1) ^ plx)]);
        bp[g] = f.v;
      }
      __builtin_amdgcn_s_setprio(1);
      #pragma unroll
      for (int t2 = 0; t2 < 4; t2++) {
        bf16x8 av = *reinterpret_cast<const bf16x8*>(vts + (16 * t2 + lr) * 64 + sw);
        #pragma unroll
        for (int g = 0; g < 4; g++)
          o_acc[g][t2] = __builtin_amdgcn_mfma_f32_16x16x32_bf16(av, bp[g], o_acc[g][t2], 0, 0, 0);
      }
      __builtin_amdgcn_s_setprio(0);
    };

    // A: QK^T keys 0-31 -> P
    qkt(0);
    qkt(1);
    __builtin_amdgcn_wave_barrier();  // pin ds_write -> ds_read (same wave)
    // B: PV kc=0 (consumes P fully)
    pv(sw0);
    __builtin_amdgcn_wave_barrier();  // pin B reads -> C overwrites
    // C: QK^T keys 32-63 -> P (overwrite)
    qkt(2);
    qkt(3);
    __builtin_amdgcn_wave_barrier();  // pin ds_write -> ds_read
    // D: PV kc=1
    pv(sw1);

    kpf += (size_t)64 * HD_;
    vpf += 64;
    __syncthreads();  // frees cur buf; drains prefetch -> tile it+1 ready
  }

  // finish denom: sum across the 4 lq groups sharing q=lr
  #pragma unroll
  for (int g = 0; g < 4; g++) {
    l_i[g] += __shfl_xor(l_i[g], 16, 64);
    l_i[g] += __shfl_xor(l_i[g], 32, 64);
  }

  // epilogue: out[b, s=q0+64w+16g+lr, h*64 + 16t + 4lq + r]
  const int b = bh >> 4, h = bh & 15;
  #pragma unroll
  for (int g = 0; g < 4; g++) {
    const float inv = 1.0f / l_i[g];
    const int qrow = q0 + 64 * w + 16 * g + lr;
    bf16* orow = out + ((size_t)b * S_ + qrow) * D_ + h * HD_;
    #pragma unroll
    for (int t = 0; t < 4; t++) {
      bf16x4 pk;
      #pragma unroll
      for (int r = 0; r < 4; r++) pk[r] = (bf16)(o_acc[g][t][r] * inv);
      *reinterpret_cast<bf16x4*>(&orow[16 * t + lq * 4]) = pk;
    }
  }
}

// ---------------------------------------------------------------------------
extern "C" void kernel_launch(void* const* d_in, const int* in_sizes, int n_in,
                              void* d_out, int out_size, void* d_ws, size_t ws_size,
                              hipStream_t stream) {
  const float* X_Q   = (const float*)d_in[0];
  const float* X_KV  = (const float*)d_in[1];
  const float* q_w   = (const float*)d_in[2];
  const float* q_b   = (const float*)d_in[3];
  const float* kv_w  = (const float*)d_in[4];
  const float* kv_b  = (const float*)d_in[5];
  const float* out_w = (const float*)d_in[6];
  const float* out_b = (const float*)d_in[7];
  float* out = (float*)d_out;

  char* ws = (char*)d_ws;
  const size_t MB = 1024 * 1024;
  bf16* Xq   = (bf16*)(ws + 0);         // 16MB (reused as attn output later)
  bf16* Xkv  = (bf16*)(ws + 16 * MB);   // 16MB
  bf16* Qb   = (bf16*)(ws + 32 * MB);   // 16MB  [B,H,S,HD] (pre-scaled)
  bf16* Kb   = (bf16*)(ws + 48 * MB);   // 16MB  [B,H,S,HD]; Vt follows at +16MB
  bf16* qwT  = (bf16*)(ws + 80 * MB);   // 2MB   [N=1024][K=1024]
  bf16* kvwT = (bf16*)(ws + 82 * MB);   // 4MB   [N=2048][K=1024]
  bf16* owT  = (bf16*)(ws + 86 * MB);   // 2MB
  bf16* Vt   = Kb + (size_t)B_ * H_ * S_ * HD_;  // [B,H,HD,S]
  bf16* attn = Xq;                       // alias: X_Q bf16 dead after GEMM1

  cast_both<<<16384, 256, 0, stream>>>(X_Q, Xq, X_KV, Xkv);
  transcast_all<<<4096, 256, 0, stream>>>(q_w, qwT, kv_w, kvwT, out_w, owT);

  // merged: Q = (Xq @ q_w + q_b)*QSCALE  and  KV = Xkv @ kv_w + kv_b
  gemm_qkv<<<1536, 256, 0, stream>>>(Xq, qwT, q_b, Qb, Xkv, kvwT, kv_b, Kb);
  // attention (512 q-rows per block, 8 waves; bh-major grid for XCD/L2)
  attn_kernel<<<dim3(64, 4), 512, 0, stream>>>(Qb, Kb, Vt, attn);
  // out = attn @ out_w + out_b  (fp32)
  gemm_out<<<dim3(8, 64), 256, 0, stream>>>(attn, owT, out_b, out, 8192, 1024, 1024);
}